// Round 16
// baseline (177.549 us; speedup 1.0000x reference)
//
#include <hip/hip_runtime.h>
#include <hip/hip_bf16.h>

#define DEVI __device__ __forceinline__

using u16 = unsigned short;
typedef __attribute__((ext_vector_type(8))) short bf16x8;
typedef __attribute__((ext_vector_type(4))) short bf16x4;
typedef __attribute__((ext_vector_type(4))) float f32x4;

constexpr int Bb = 4, Ls = 2048, Dd = 1024, Hh = 16, DhC = 64;
constexpr int Mm = Bb * Ls; // 8192

DEVI u16 f2bf(float f) {
  union { float f; unsigned u; } x; x.f = f;
  unsigned r = x.u + 0x7FFFu + ((x.u >> 16) & 1u);
  return (u16)(r >> 16);
}
DEVI float bf2f(u16 b) {
  union { unsigned u; float f; } x; x.u = ((unsigned)b) << 16;
  return x.f;
}

// pack two f32 -> two bf16 (RTNE): D[15:0]=bf16(a), D[31:16]=bf16(b)
DEVI unsigned cvt_pk_bf16(float a, float b) {
  unsigned d;
  asm("v_cvt_pk_bf16_f32 %0, %1, %2" : "=v"(d) : "v"(a), "v"(b));
  return d;
}

DEVI void gload_lds16(const u16* g, u16* l) {
  __builtin_amdgcn_global_load_lds(
      (const __attribute__((address_space(1))) unsigned int*)g,
      (__attribute__((address_space(3))) unsigned int*)l, 16, 0, 0);
}

DEVI bf16x8 ld_frag(const u16* p) { return *reinterpret_cast<const bf16x8*>(p); }

// single launch: x (8192x1024) + all four 1024x1024 weights
__global__ void cvt_all(const float* __restrict__ x,
                        const float* __restrict__ wq, const float* __restrict__ wk,
                        const float* __restrict__ wv, const float* __restrict__ wo,
                        u16* __restrict__ xb,
                        u16* __restrict__ wqb, u16* __restrict__ wkb,
                        u16* __restrict__ wvb, u16* __restrict__ wob) {
  const int tid = blockIdx.x * blockDim.x + threadIdx.x;  // grid 2048 x 256
  constexpr int NT = 2048 * 256;
  constexpr int N4X = Mm * Dd / 4;
  constexpr int N4W = Dd * Dd / 4;
  for (int i = tid; i < N4X; i += NT) {
    float4 v = reinterpret_cast<const float4*>(x)[i];
    reinterpret_cast<ushort4*>(xb)[i] =
        make_ushort4(f2bf(v.x), f2bf(v.y), f2bf(v.z), f2bf(v.w));
  }
  for (int i = tid; i < 4 * N4W; i += NT) {
    int which = i / N4W, off = i - which * N4W;
    const float* s = which == 0 ? wq : which == 1 ? wk : which == 2 ? wv : wo;
    u16* d = which == 0 ? wqb : which == 1 ? wkb : which == 2 ? wvb : wob;
    float4 v = reinterpret_cast<const float4*>(s)[off];
    reinterpret_cast<ushort4*>(d)[off] =
        make_ushort4(f2bf(v.x), f2bf(v.y), f2bf(v.z), f2bf(v.w));
  }
}

// Fused QKV projection, 128x256 2-phase + triple-buffered LDS (R15, proven).
__global__ __launch_bounds__(512) void gemm_qkv(
    const u16* __restrict__ A, const u16* __restrict__ W,
    const float* __restrict__ bq, const float* __restrict__ bk2,
    const float* __restrict__ bv,
    u16* __restrict__ qm, u16* __restrict__ km, u16* __restrict__ vt)
{
  constexpr int K = 1024, BK = 64, NSTEP = K / BK;  // 16
  __shared__ u16 ldsA[3][128 * 64];                 // 48 KiB
  __shared__ u16 ldsB[3][256 * 64];                 // 96 KiB

  const int tid = threadIdx.x;
  const int wave = tid >> 6, lane = tid & 63;
  const int wr = wave >> 2, wc = wave & 3;          // 2M x 4N waves
  const int lrow = lane & 15, hi = lane >> 4, lk = hi * 8;
  const int swz = (lrow & 7) << 3;

  const int lin = blockIdx.y * 12 + blockIdx.x;     // 0..767
  const int nid = (lin & 7) * 96 + (lin >> 3);      // bijective (768/8=96)
  const int bx = nid % 12, by = nid / 12;
  const int m0 = by * 128;
  const int n0g = bx * 256;

  int a_row[2], a_kc[2], b_row[4], b_kc[4];
#pragma unroll
  for (int g = 0; g < 2; ++g) {
    int c = g * 512 + tid;
    a_row[g] = c >> 3;
    a_kc[g] = ((c & 7) ^ (a_row[g] & 7)) * 8;
  }
#pragma unroll
  for (int g = 0; g < 4; ++g) {
    int c = g * 512 + tid;
    b_row[g] = c >> 3;
    b_kc[g] = ((c & 7) ^ (b_row[g] & 7)) * 8;
  }

  f32x4 acc[4][4] = {};

  // prologue: stage tile0 -> buf0 and tile1 -> buf1; wait tile0 only
#pragma unroll
  for (int g = 0; g < 2; ++g)
    gload_lds16(A + (size_t)(m0 + a_row[g]) * K + a_kc[g], &ldsA[0][0] + (g * 512 + tid) * 8);
#pragma unroll
  for (int g = 0; g < 4; ++g)
    gload_lds16(W + (size_t)(n0g + b_row[g]) * K + b_kc[g], &ldsB[0][0] + (g * 512 + tid) * 8);
#pragma unroll
  for (int g = 0; g < 2; ++g)
    gload_lds16(A + (size_t)(m0 + a_row[g]) * K + BK + a_kc[g], &ldsA[1][0] + (g * 512 + tid) * 8);
#pragma unroll
  for (int g = 0; g < 4; ++g)
    gload_lds16(W + (size_t)(n0g + b_row[g]) * K + BK + b_kc[g], &ldsB[1][0] + (g * 512 + tid) * 8);
  asm volatile("s_waitcnt vmcnt(6)" ::: "memory");
  __syncthreads();

  int cur = 0, nx2 = 2;   // t%3, (t+2)%3
  for (int t = 0; t < NSTEP; ++t) {
    const u16* Ab = &ldsA[cur][0];
    const u16* Bb = &ldsB[cur][0];
    u16* An = &ldsA[nx2][0];
    u16* Bn = &ldsB[nx2][0];
    const int k2 = (t + 2) * BK;
    const bool more2 = (t + 2 < NSTEP);

    bf16x8 a[4][2], b0[2][2], b1[2][2];

    // ---- phase 0
#pragma unroll
    for (int f = 0; f < 4; ++f) {
      int row = wr * 64 + f * 16 + lrow;
      a[f][0] = ld_frag(Ab + row * 64 + (lk ^ swz));
      a[f][1] = ld_frag(Ab + row * 64 + ((32 + lk) ^ swz));
    }
#pragma unroll
    for (int f = 0; f < 2; ++f) {
      int row = wc * 64 + f * 16 + lrow;
      b0[f][0] = ld_frag(Bb + row * 64 + (lk ^ swz));
      b0[f][1] = ld_frag(Bb + row * 64 + ((32 + lk) ^ swz));
    }
    if (more2) {
      gload_lds16(A + (size_t)(m0 + a_row[0]) * K + k2 + a_kc[0], An + (0 * 512 + tid) * 8);
      gload_lds16(A + (size_t)(m0 + a_row[1]) * K + k2 + a_kc[1], An + (1 * 512 + tid) * 8);
      gload_lds16(W + (size_t)(n0g + b_row[0]) * K + k2 + b_kc[0], Bn + (0 * 512 + tid) * 8);
    }
    __builtin_amdgcn_s_barrier();
    __builtin_amdgcn_s_setprio(1);
#pragma unroll
    for (int fm = 0; fm < 4; ++fm)
#pragma unroll
      for (int fn = 0; fn < 2; ++fn)
#pragma unroll
        for (int kk = 0; kk < 2; ++kk)
          acc[fm][fn] = __builtin_amdgcn_mfma_f32_16x16x32_bf16(a[fm][kk], b0[fn][kk], acc[fm][fn], 0, 0, 0);
    __builtin_amdgcn_s_setprio(0);
    __builtin_amdgcn_s_barrier();

    // ---- phase 1
#pragma unroll
    for (int f = 0; f < 2; ++f) {
      int row = wc * 64 + (2 + f) * 16 + lrow;
      b1[f][0] = ld_frag(Bb + row * 64 + (lk ^ swz));
      b1[f][1] = ld_frag(Bb + row * 64 + ((32 + lk) ^ swz));
    }
    if (more2) {
      gload_lds16(W + (size_t)(n0g + b_row[1]) * K + k2 + b_kc[1], Bn + (1 * 512 + tid) * 8);
      gload_lds16(W + (size_t)(n0g + b_row[2]) * K + k2 + b_kc[2], Bn + (2 * 512 + tid) * 8);
      gload_lds16(W + (size_t)(n0g + b_row[3]) * K + k2 + b_kc[3], Bn + (3 * 512 + tid) * 8);
    }
    __builtin_amdgcn_s_barrier();
    __builtin_amdgcn_s_setprio(1);
#pragma unroll
    for (int fm = 0; fm < 4; ++fm)
#pragma unroll
      for (int fn = 0; fn < 2; ++fn)
#pragma unroll
        for (int kk = 0; kk < 2; ++kk)
          acc[fm][2 + fn] = __builtin_amdgcn_mfma_f32_16x16x32_bf16(a[fm][kk], b1[fn][kk], acc[fm][2 + fn], 0, 0, 0);
    __builtin_amdgcn_s_setprio(0);
    if (t + 1 < NSTEP) {
      if (more2) asm volatile("s_waitcnt vmcnt(6)" ::: "memory");
      else       asm volatile("s_waitcnt vmcnt(0)" ::: "memory");
    }
    __builtin_amdgcn_s_barrier();
    cur = cur == 2 ? 0 : cur + 1;
    nx2 = nx2 == 2 ? 0 : nx2 + 1;
  }

  const int region = bx >> 2;               // 0=q, 1=k, 2=v
  const int nc0 = (bx & 3) * 256;
  const float* bias = region == 0 ? bq : region == 1 ? bk2 : bv;
  u16* dstRM = region == 0 ? qm : km;

#pragma unroll
  for (int fm = 0; fm < 4; ++fm) {
#pragma unroll
    for (int fn = 0; fn < 4; ++fn) {
      int row = m0 + wr * 64 + fm * 16 + hi * 4;
      int col = nc0 + wc * 64 + fn * 16 + lrow;
      float bv_ = bias[col];
      if (region == 2) {
        ushort4 o;
        o.x = f2bf(acc[fm][fn][0] + bv_); o.y = f2bf(acc[fm][fn][1] + bv_);
        o.z = f2bf(acc[fm][fn][2] + bv_); o.w = f2bf(acc[fm][fn][3] + bv_);
        *reinterpret_cast<ushort4*>(&vt[(size_t)col * Mm + row]) = o;
      } else {
#pragma unroll
        for (int j = 0; j < 4; ++j)
          dstRM[(size_t)(row + j) * Dd + col] = f2bf(acc[fm][fn][j] + bv_);
      }
    }
  }
}

// Out-projection GEMM: same 128x256 2-phase + triple-buffer (R15). f32 out.
__global__ __launch_bounds__(512) void gemm_out(
    const u16* __restrict__ A, const u16* __restrict__ Bt,
    const float* __restrict__ bias, float* __restrict__ C)
{
  constexpr int K = 1024, N = 1024, BK = 64, NSTEP = K / BK;
  __shared__ u16 ldsA[3][128 * 64];
  __shared__ u16 ldsB[3][256 * 64];

  const int tid = threadIdx.x;
  const int wave = tid >> 6, lane = tid & 63;
  const int wr = wave >> 2, wc = wave & 3;
  const int lrow = lane & 15, hi = lane >> 4, lk = hi * 8;
  const int swz = (lrow & 7) << 3;

  const int lin = blockIdx.y * 4 + blockIdx.x;      // 0..255
  const int nid = (lin & 7) * 32 + (lin >> 3);      // bijective (256/8=32)
  const int bx = nid % 4, by = nid / 4;
  const int m0 = by * 128;
  const int n0 = bx * 256;

  int a_row[2], a_kc[2], b_row[4], b_kc[4];
#pragma unroll
  for (int g = 0; g < 2; ++g) {
    int c = g * 512 + tid;
    a_row[g] = c >> 3;
    a_kc[g] = ((c & 7) ^ (a_row[g] & 7)) * 8;
  }
#pragma unroll
  for (int g = 0; g < 4; ++g) {
    int c = g * 512 + tid;
    b_row[g] = c >> 3;
    b_kc[g] = ((c & 7) ^ (b_row[g] & 7)) * 8;
  }

  f32x4 acc[4][4] = {};

#pragma unroll
  for (int g = 0; g < 2; ++g)
    gload_lds16(A + (size_t)(m0 + a_row[g]) * K + a_kc[g], &ldsA[0][0] + (g * 512 + tid) * 8);
#pragma unroll
  for (int g = 0; g < 4; ++g)
    gload_lds16(Bt + (size_t)(n0 + b_row[g]) * K + b_kc[g], &ldsB[0][0] + (g * 512 + tid) * 8);
#pragma unroll
  for (int g = 0; g < 2; ++g)
    gload_lds16(A + (size_t)(m0 + a_row[g]) * K + BK + a_kc[g], &ldsA[1][0] + (g * 512 + tid) * 8);
#pragma unroll
  for (int g = 0; g < 4; ++g)
    gload_lds16(Bt + (size_t)(n0 + b_row[g]) * K + BK + b_kc[g], &ldsB[1][0] + (g * 512 + tid) * 8);
  asm volatile("s_waitcnt vmcnt(6)" ::: "memory");
  __syncthreads();

  int cur = 0, nx2 = 2;
  for (int t = 0; t < NSTEP; ++t) {
    const u16* Ab = &ldsA[cur][0];
    const u16* Bb = &ldsB[cur][0];
    u16* An = &ldsA[nx2][0];
    u16* Bn = &ldsB[nx2][0];
    const int k2 = (t + 2) * BK;
    const bool more2 = (t + 2 < NSTEP);

    bf16x8 a[4][2], b0[2][2], b1[2][2];

#pragma unroll
    for (int f = 0; f < 4; ++f) {
      int row = wr * 64 + f * 16 + lrow;
      a[f][0] = ld_frag(Ab + row * 64 + (lk ^ swz));
      a[f][1] = ld_frag(Ab + row * 64 + ((32 + lk) ^ swz));
    }
#pragma unroll
    for (int f = 0; f < 2; ++f) {
      int row = wc * 64 + f * 16 + lrow;
      b0[f][0] = ld_frag(Bb + row * 64 + (lk ^ swz));
      b0[f][1] = ld_frag(Bb + row * 64 + ((32 + lk) ^ swz));
    }
    if (more2) {
      gload_lds16(A + (size_t)(m0 + a_row[0]) * K + k2 + a_kc[0], An + (0 * 512 + tid) * 8);
      gload_lds16(A + (size_t)(m0 + a_row[1]) * K + k2 + a_kc[1], An + (1 * 512 + tid) * 8);
      gload_lds16(Bt + (size_t)(n0 + b_row[0]) * K + k2 + b_kc[0], Bn + (0 * 512 + tid) * 8);
    }
    __builtin_amdgcn_s_barrier();
    __builtin_amdgcn_s_setprio(1);
#pragma unroll
    for (int fm = 0; fm < 4; ++fm)
#pragma unroll
      for (int fn = 0; fn < 2; ++fn)
#pragma unroll
        for (int kk = 0; kk < 2; ++kk)
          acc[fm][fn] = __builtin_amdgcn_mfma_f32_16x16x32_bf16(a[fm][kk], b0[fn][kk], acc[fm][fn], 0, 0, 0);
    __builtin_amdgcn_s_setprio(0);
    __builtin_amdgcn_s_barrier();

#pragma unroll
    for (int f = 0; f < 2; ++f) {
      int row = wc * 64 + (2 + f) * 16 + lrow;
      b1[f][0] = ld_frag(Bb + row * 64 + (lk ^ swz));
      b1[f][1] = ld_frag(Bb + row * 64 + ((32 + lk) ^ swz));
    }
    if (more2) {
      gload_lds16(Bt + (size_t)(n0 + b_row[1]) * K + k2 + b_kc[1], Bn + (1 * 512 + tid) * 8);
      gload_lds16(Bt + (size_t)(n0 + b_row[2]) * K + k2 + b_kc[2], Bn + (2 * 512 + tid) * 8);
      gload_lds16(Bt + (size_t)(n0 + b_row[3]) * K + k2 + b_kc[3], Bn + (3 * 512 + tid) * 8);
    }
    __builtin_amdgcn_s_barrier();
    __builtin_amdgcn_s_setprio(1);
#pragma unroll
    for (int fm = 0; fm < 4; ++fm)
#pragma unroll
      for (int fn = 0; fn < 2; ++fn)
#pragma unroll
        for (int kk = 0; kk < 2; ++kk)
          acc[fm][2 + fn] = __builtin_amdgcn_mfma_f32_16x16x32_bf16(a[fm][kk], b1[fn][kk], acc[fm][2 + fn], 0, 0, 0);
    __builtin_amdgcn_s_setprio(0);
    if (t + 1 < NSTEP) {
      if (more2) asm volatile("s_waitcnt vmcnt(6)" ::: "memory");
      else       asm volatile("s_waitcnt vmcnt(0)" ::: "memory");
    }
    __builtin_amdgcn_s_barrier();
    cur = cur == 2 ? 0 : cur + 1;
    nx2 = nx2 == 2 ? 0 : nx2 + 1;
  }

#pragma unroll
  for (int fm = 0; fm < 4; ++fm) {
#pragma unroll
    for (int fn = 0; fn < 4; ++fn) {
      int row = m0 + wr * 64 + fm * 16 + hi * 4;
      int col = n0 + wc * 64 + fn * 16 + lrow;
      float bv = bias[col];
#pragma unroll
      for (int j = 0; j < 4; ++j)
        C[(size_t)(row + j) * N + col] = acc[fm][fn][j] + bv;
    }
  }
}

// Flash attention, 2 q-blocks/wave. THIS ROUND: KVBLK 64 -> 128 (sync-event
// halving): 128-key K/V tiles double-buffered (64KB LDS, still 2 blocks/CU),
// processed as two 64-key sub-tiles between ONE barrier pair; barriers and
// vmcnt waits per key halved, 16 loop iterations instead of 32.
// V^T tile is [64][128] (row stride 256B): chunk-XOR swizzle re-derived —
// low-3 bits of the 16B-chunk index XOR (row&7); read expr (kk2*32+lk)^swz
// + s*64; staged via pre-swizzled global source (rule #21 both-sides).
// Q staging fills exactly the whole Ks dbuf (256x64 = 32KB).
__global__ __launch_bounds__(512) void attn_fwd(
    const u16* __restrict__ Qm, const u16* __restrict__ Km,
    const u16* __restrict__ Vt, u16* __restrict__ Om)
{
  __shared__ u16 Ks[2][8192];      // K tile dbuf 128x64; Q staging (256x64)
  __shared__ u16 Vs[2][8192];      // V^T tile dbuf 64x128

  const int tid = threadIdx.x;
  const int wave = tid >> 6, lane = tid & 63;
  const int lrow = lane & 15, hi = lane >> 4, lk = hi * 8;
  const int swz = (lrow & 7) << 3;
  const int b = blockIdx.x >> 4, h = blockIdx.x & 15;
  const int rb = b * Ls;
  const int cb0 = h * DhC;
  const int q0 = blockIdx.y * 256;

  u16* ksflat = &Ks[0][0];
  u16* vsflat = &Vs[0][0];
  constexpr int LBUF = 8192;

  // K staging: 1024 chunks/tile, 2 per thread (rows 0..127, 8 chunks/row)
  int k_row[2], k_kc[2];
#pragma unroll
  for (int g = 0; g < 2; ++g) {
    int c = g * 512 + tid;
    k_row[g] = c >> 3;
    k_kc[g] = ((c & 7) ^ (k_row[g] & 7)) * 8;
  }
  // V staging: 1024 chunks/tile (rows dh 0..63, 16 chunks/row); low-3-bit XOR
  int v_row[2], v_sc[2];
#pragma unroll
  for (int g = 0; g < 2; ++g) {
    int c = g * 512 + tid;
    v_row[g] = c >> 4;
    v_sc[g] = (((c & 7) ^ (v_row[g] & 7)) + (c & 8)) * 8;
  }
  const u16* kg0 = Km + (size_t)(rb + k_row[0]) * Dd + cb0 + k_kc[0];
  const u16* kg1 = Km + (size_t)(rb + k_row[1]) * Dd + cb0 + k_kc[1];
  const u16* vg0 = Vt + (size_t)(cb0 + v_row[0]) * Mm + rb + v_sc[0];
  const u16* vg1 = Vt + (size_t)(cb0 + v_row[1]) * Mm + rb + v_sc[1];

  // prologue: Q (256x64 = 32KB) -> entire Ks dbuf (2048 chunks, 4/thread)
#pragma unroll
  for (int g = 0; g < 4; ++g) {
    int c = g * 512 + tid;
    int row = c >> 3;
    gload_lds16(Qm + (size_t)(rb + q0 + row) * Dd + cb0 + ((c & 7) ^ (row & 7)) * 8,
                ksflat + c * 8);
  }
  __syncthreads();

  constexpr float SCL = 0.25f * 1.44269504088896f;
  bf16x8 aq[2][2];
#pragma unroll
  for (int t = 0; t < 2; ++t) {
    int row = wave * 32 + t * 16 + lrow;      // 0..255
    const u16* base = ksflat + row * 64;
    aq[t][0] = ld_frag(base + (lk ^ swz));
    aq[t][1] = ld_frag(base + ((32 + lk) ^ swz));
#pragma unroll
    for (int e = 0; e < 8; e += 2) {
      unsigned d0 = cvt_pk_bf16(SCL * bf2f((u16)aq[t][0][e]), SCL * bf2f((u16)aq[t][0][e + 1]));
      unsigned d1 = cvt_pk_bf16(SCL * bf2f((u16)aq[t][1][e]), SCL * bf2f((u16)aq[t][1][e + 1]));
      aq[t][0][e] = (short)(d0 & 0xffff); aq[t][0][e + 1] = (short)(d0 >> 16);
      aq[t][1][e] = (short)(d1 & 0xffff); aq[t][1][e + 1] = (short)(d1 >> 16);
    }
  }
  __syncthreads();   // all waves done reading Q
  // stage K0,V0 into buf 0 (overwrites Q staging area)
  gload_lds16(kg0, ksflat + (0 * 512 + tid) * 8);
  gload_lds16(kg1, ksflat + (1 * 512 + tid) * 8);
  gload_lds16(vg0, vsflat + (0 * 512 + tid) * 8);
  gload_lds16(vg1, vsflat + (1 * 512 + tid) * 8);

  bf16x8 ones;
#pragma unroll
  for (int e = 0; e < 8; ++e) ones[e] = (short)0x3F80;

  f32x4 accO[2][4] = {};
  f32x4 acc_ps[2] = {};

#define SM_PACK(SIN, AP0, AP1)                                                 \
  {                                                                            \
    unsigned u00 = cvt_pk_bf16(__builtin_amdgcn_exp2f(SIN[0][0]), __builtin_amdgcn_exp2f(SIN[0][1])); \
    unsigned u01 = cvt_pk_bf16(__builtin_amdgcn_exp2f(SIN[0][2]), __builtin_amdgcn_exp2f(SIN[0][3])); \
    unsigned u10 = cvt_pk_bf16(__builtin_amdgcn_exp2f(SIN[1][0]), __builtin_amdgcn_exp2f(SIN[1][1])); \
    unsigned u11 = cvt_pk_bf16(__builtin_amdgcn_exp2f(SIN[1][2]), __builtin_amdgcn_exp2f(SIN[1][3])); \
    unsigned u20 = cvt_pk_bf16(__builtin_amdgcn_exp2f(SIN[2][0]), __builtin_amdgcn_exp2f(SIN[2][1])); \
    unsigned u21 = cvt_pk_bf16(__builtin_amdgcn_exp2f(SIN[2][2]), __builtin_amdgcn_exp2f(SIN[2][3])); \
    unsigned u30 = cvt_pk_bf16(__builtin_amdgcn_exp2f(SIN[3][0]), __builtin_amdgcn_exp2f(SIN[3][1])); \
    unsigned u31 = cvt_pk_bf16(__builtin_amdgcn_exp2f(SIN[3][2]), __builtin_amdgcn_exp2f(SIN[3][3])); \
    asm("v_permlane32_swap_b32 %0, %1" : "+v"(u00), "+v"(u10));                \
    asm("v_permlane16_swap_b32 %0, %1" : "+v"(u00), "+v"(u10));                \
    asm("v_permlane32_swap_b32 %0, %1" : "+v"(u01), "+v"(u11));                \
    asm("v_permlane16_swap_b32 %0, %1" : "+v"(u01), "+v"(u11));                \
    asm("v_permlane32_swap_b32 %0, %1" : "+v"(u20), "+v"(u30));                \
    asm("v_permlane16_swap_b32 %0, %1" : "+v"(u20), "+v"(u30));                \
    asm("v_permlane32_swap_b32 %0, %1" : "+v"(u21), "+v"(u31));                \
    asm("v_permlane16_swap_b32 %0, %1" : "+v"(u21), "+v"(u31));                \
    union { unsigned u[4]; bf16x8 v; } c0_, c1_;                               \
    c0_.u[0] = u00; c0_.u[1] = u01; c0_.u[2] = u10; c0_.u[3] = u11;            \
    c1_.u[0] = u20; c1_.u[1] = u21; c1_.u[2] = u30; c1_.u[3] = u31;            \
    AP0 = c0_.v; AP1 = c1_.v;                                                  \
  }

  for (int t = 0; t < 16; ++t) {
    if (t < 15) {
      int dst = ((t + 1) & 1) * LBUF;
      size_t koff = (size_t)(128 * (t + 1)) * Dd;
      int vcoff = 128 * (t + 1);
      gload_lds16(kg0 + koff, ksflat + dst + (0 * 512 + tid) * 8);
      gload_lds16(kg1 + koff, ksflat + dst + (1 * 512 + tid) * 8);
      gload_lds16(vg0 + vcoff, vsflat + dst + (0 * 512 + tid) * 8);
      gload_lds16(vg1 + vcoff, vsflat + dst + (1 * 512 + tid) * 8);
      asm volatile("s_waitcnt vmcnt(4)" ::: "memory");  // tile t landed
    } else {
      asm volatile("s_waitcnt vmcnt(0)" ::: "memory");
    }
    __builtin_amdgcn_s_barrier();
    const u16* ks = ksflat + (t & 1) * LBUF;
    const u16* vs = vsflat + (t & 1) * LBUF;

#pragma unroll
    for (int s = 0; s < 2; ++s) {
      // K fragments for this 64-key sub-tile
      bf16x8 bk[4][2];
#pragma unroll
      for (int kb = 0; kb < 4; ++kb) {
        const u16* kr = ks + (s * 64 + kb * 16 + lrow) * 64;
        bk[kb][0] = ld_frag(kr + (lk ^ swz));
        bk[kb][1] = ld_frag(kr + ((32 + lk) ^ swz));
      }

      f32x4 s0[4], s1[4];
      __builtin_amdgcn_s_setprio(1);
#pragma unroll
      for (int kb = 0; kb < 4; ++kb) {
        f32x4 u = {};
        u = __builtin_amdgcn_mfma_f32_16x16x32_bf16(bk[kb][0], aq[0][0], u, 0, 0, 0);
        u = __builtin_amdgcn_mfma_f32_16x16x32_bf16(bk[kb][1], aq[0][1], u, 0, 0, 0);
        s0[kb] = u;
      }
#pragma unroll
      for (int kb = 0; kb < 4; ++kb) {
        f32x4 u = {};
        u = __builtin_amdgcn_mfma_f32_16x16x32_bf16(bk[kb][0], aq[1][0], u, 0, 0, 0);
        u = __builtin_amdgcn_mfma_f32_16x16x32_bf16(bk[kb][1], aq[1][1], u, 0, 0, 0);
        s1[kb] = u;
      }
      __builtin_amdgcn_s_setprio(0);

      bf16x8 ap0[2], ap1[2];
      SM_PACK(s0, ap0[0], ap0[1]);
      SM_PACK(s1, ap1[0], ap1[1]);

#pragma unroll
      for (int kk2 = 0; kk2 < 2; ++kk2) {
        __builtin_amdgcn_s_setprio(1);
#pragma unroll
        for (int cb = 0; cb < 4; ++cb) {
          const u16* vr = vs + (cb * 16 + lrow) * 128 + s * 64;
          bf16x8 bv = ld_frag(vr + ((kk2 * 32 + lk) ^ swz));
          accO[0][cb] = __builtin_amdgcn_mfma_f32_16x16x32_bf16(bv, ap0[kk2], accO[0][cb], 0, 0, 0);
          accO[1][cb] = __builtin_amdgcn_mfma_f32_16x16x32_bf16(bv, ap1[kk2], accO[1][cb], 0, 0, 0);
        }
        acc_ps[0] = __builtin_amdgcn_mfma_f32_16x16x32_bf16(ones, ap0[kk2], acc_ps[0], 0, 0, 0);
        acc_ps[1] = __builtin_amdgcn_mfma_f32_16x16x32_bf16(ones, ap1[kk2], acc_ps[1], 0, 0, 0);
        __builtin_amdgcn_s_setprio(0);
      }
    }

    if (t < 15) __builtin_amdgcn_s_barrier();  // WAR before t+1 overwrites buf
  }
#undef SM_PACK

#pragma unroll
  for (int t = 0; t < 2; ++t) {
    float rinv = 1.0f / acc_ps[t][0];
    const size_t orow = (size_t)(rb + q0 + wave * 32 + t * 16 + lrow) * Dd + cb0;
#pragma unroll
    for (int cb = 0; cb < 4; ++cb) {
      uint2 o;
      o.x = cvt_pk_bf16(accO[t][cb][0] * rinv, accO[t][cb][1] * rinv);
      o.y = cvt_pk_bf16(accO[t][cb][2] * rinv, accO[t][cb][3] * rinv);
      *reinterpret_cast<uint2*>(&Om[orow + cb * 16 + (lk >> 1)]) = o;
    }
  }
}

extern "C" void kernel_launch(void* const* d_in, const int* in_sizes, int n_in,
                              void* d_out, int out_size, void* d_ws, size_t ws_size,
                              hipStream_t stream) {
  (void)in_sizes; (void)n_in; (void)out_size; (void)ws_size;
  const float* x  = (const float*)d_in[0];
  const float* wq = (const float*)d_in[1];
  const float* bq = (const float*)d_in[2];
  const float* wk = (const float*)d_in[3];
  const float* bk = (const float*)d_in[4];
  const float* wv = (const float*)d_in[5];
  const float* bv = (const float*)d_in[6];
  const float* wo = (const float*)d_in[7];
  const float* bo = (const float*)d_in[8];
  float* out = (float*)d_out;

  u16* ws  = (u16*)d_ws;
  u16* xb  = ws;
  u16* wqb = xb  + (size_t)Mm * Dd;
  u16* wkb = wqb + (size_t)Dd * Dd;
  u16* wvb = wkb + (size_t)Dd * Dd;
  u16* wob = wvb + (size_t)Dd * Dd;
  u16* qm  = wob + (size_t)Dd * Dd;
  u16* km  = qm  + (size_t)Mm * Dd;
  u16* vt  = km  + (size_t)Mm * Dd;
  u16* om  = xb;

  cvt_all<<<2048, 256, 0, stream>>>(x, wq, wk, wv, wo, xb, wqb, wkb, wvb, wob);

  dim3 qkvgrid(3 * Dd / 256, Mm / 128);   // 12 x 64 = 768 blocks, zero tail
  gemm_qkv<<<qkvgrid, 512, 0, stream>>>(xb, wqb, bq, bk, bv, qm, km, vt);

  dim3 agrid(Bb * Hh, Ls / 256);          // 64 x 8 = 512 blocks, 2/CU
  attn_fwd<<<agrid, 512, 0, stream>>>(qm, km, vt, om);

  dim3 ogrid(Dd / 256, Mm / 128);         // 4 x 64 = 256 blocks, 1/CU
  gemm_out<<<ogrid, 512, 0, stream>>>(om, wob, bo, out);
}

// Round 17
// 169.651 us; speedup vs baseline: 1.0466x; 1.0466x over previous
//
#include <hip/hip_runtime.h>
#include <hip/hip_bf16.h>

#define DEVI __device__ __forceinline__

using u16 = unsigned short;
typedef __attribute__((ext_vector_type(8))) short bf16x8;
typedef __attribute__((ext_vector_type(4))) short bf16x4;
typedef __attribute__((ext_vector_type(4))) float f32x4;

constexpr int Bb = 4, Ls = 2048, Dd = 1024, Hh = 16, DhC = 64;
constexpr int Mm = Bb * Ls; // 8192

DEVI u16 f2bf(float f) {
  union { float f; unsigned u; } x; x.f = f;
  unsigned r = x.u + 0x7FFFu + ((x.u >> 16) & 1u);
  return (u16)(r >> 16);
}
DEVI float bf2f(u16 b) {
  union { unsigned u; float f; } x; x.u = ((unsigned)b) << 16;
  return x.f;
}

// pack two f32 -> two bf16 (RTNE): D[15:0]=bf16(a), D[31:16]=bf16(b)
DEVI unsigned cvt_pk_bf16(float a, float b) {
  unsigned d;
  asm("v_cvt_pk_bf16_f32 %0, %1, %2" : "=v"(d) : "v"(a), "v"(b));
  return d;
}

DEVI void gload_lds16(const u16* g, u16* l) {
  __builtin_amdgcn_global_load_lds(
      (const __attribute__((address_space(1))) unsigned int*)g,
      (__attribute__((address_space(3))) unsigned int*)l, 16, 0, 0);
}

DEVI bf16x8 ld_frag(const u16* p) { return *reinterpret_cast<const bf16x8*>(p); }

// single launch: x (8192x1024) + all four 1024x1024 weights
__global__ void cvt_all(const float* __restrict__ x,
                        const float* __restrict__ wq, const float* __restrict__ wk,
                        const float* __restrict__ wv, const float* __restrict__ wo,
                        u16* __restrict__ xb,
                        u16* __restrict__ wqb, u16* __restrict__ wkb,
                        u16* __restrict__ wvb, u16* __restrict__ wob) {
  const int tid = blockIdx.x * blockDim.x + threadIdx.x;  // grid 2048 x 256
  constexpr int NT = 2048 * 256;
  constexpr int N4X = Mm * Dd / 4;
  constexpr int N4W = Dd * Dd / 4;
  for (int i = tid; i < N4X; i += NT) {
    float4 v = reinterpret_cast<const float4*>(x)[i];
    reinterpret_cast<ushort4*>(xb)[i] =
        make_ushort4(f2bf(v.x), f2bf(v.y), f2bf(v.z), f2bf(v.w));
  }
  for (int i = tid; i < 4 * N4W; i += NT) {
    int which = i / N4W, off = i - which * N4W;
    const float* s = which == 0 ? wq : which == 1 ? wk : which == 2 ? wv : wo;
    u16* d = which == 0 ? wqb : which == 1 ? wkb : which == 2 ? wvb : wob;
    float4 v = reinterpret_cast<const float4*>(s)[off];
    reinterpret_cast<ushort4*>(d)[off] =
        make_ushort4(f2bf(v.x), f2bf(v.y), f2bf(v.z), f2bf(v.w));
  }
}

// Fused QKV projection, 128x256 2-phase + triple-buffered LDS (R15, proven).
__global__ __launch_bounds__(512) void gemm_qkv(
    const u16* __restrict__ A, const u16* __restrict__ W,
    const float* __restrict__ bq, const float* __restrict__ bk2,
    const float* __restrict__ bv,
    u16* __restrict__ qm, u16* __restrict__ km, u16* __restrict__ vt)
{
  constexpr int K = 1024, BK = 64, NSTEP = K / BK;  // 16
  __shared__ u16 ldsA[3][128 * 64];                 // 48 KiB
  __shared__ u16 ldsB[3][256 * 64];                 // 96 KiB

  const int tid = threadIdx.x;
  const int wave = tid >> 6, lane = tid & 63;
  const int wr = wave >> 2, wc = wave & 3;          // 2M x 4N waves
  const int lrow = lane & 15, hi = lane >> 4, lk = hi * 8;
  const int swz = (lrow & 7) << 3;

  const int lin = blockIdx.y * 12 + blockIdx.x;     // 0..767
  const int nid = (lin & 7) * 96 + (lin >> 3);      // bijective (768/8=96)
  const int bx = nid % 12, by = nid / 12;
  const int m0 = by * 128;
  const int n0g = bx * 256;

  int a_row[2], a_kc[2], b_row[4], b_kc[4];
#pragma unroll
  for (int g = 0; g < 2; ++g) {
    int c = g * 512 + tid;
    a_row[g] = c >> 3;
    a_kc[g] = ((c & 7) ^ (a_row[g] & 7)) * 8;
  }
#pragma unroll
  for (int g = 0; g < 4; ++g) {
    int c = g * 512 + tid;
    b_row[g] = c >> 3;
    b_kc[g] = ((c & 7) ^ (b_row[g] & 7)) * 8;
  }

  f32x4 acc[4][4] = {};

  // prologue: stage tile0 -> buf0 and tile1 -> buf1; wait tile0 only
#pragma unroll
  for (int g = 0; g < 2; ++g)
    gload_lds16(A + (size_t)(m0 + a_row[g]) * K + a_kc[g], &ldsA[0][0] + (g * 512 + tid) * 8);
#pragma unroll
  for (int g = 0; g < 4; ++g)
    gload_lds16(W + (size_t)(n0g + b_row[g]) * K + b_kc[g], &ldsB[0][0] + (g * 512 + tid) * 8);
#pragma unroll
  for (int g = 0; g < 2; ++g)
    gload_lds16(A + (size_t)(m0 + a_row[g]) * K + BK + a_kc[g], &ldsA[1][0] + (g * 512 + tid) * 8);
#pragma unroll
  for (int g = 0; g < 4; ++g)
    gload_lds16(W + (size_t)(n0g + b_row[g]) * K + BK + b_kc[g], &ldsB[1][0] + (g * 512 + tid) * 8);
  asm volatile("s_waitcnt vmcnt(6)" ::: "memory");
  __syncthreads();

  int cur = 0, nx2 = 2;   // t%3, (t+2)%3
  for (int t = 0; t < NSTEP; ++t) {
    const u16* Ab = &ldsA[cur][0];
    const u16* Bb = &ldsB[cur][0];
    u16* An = &ldsA[nx2][0];
    u16* Bn = &ldsB[nx2][0];
    const int k2 = (t + 2) * BK;
    const bool more2 = (t + 2 < NSTEP);

    bf16x8 a[4][2], b0[2][2], b1[2][2];

    // ---- phase 0
#pragma unroll
    for (int f = 0; f < 4; ++f) {
      int row = wr * 64 + f * 16 + lrow;
      a[f][0] = ld_frag(Ab + row * 64 + (lk ^ swz));
      a[f][1] = ld_frag(Ab + row * 64 + ((32 + lk) ^ swz));
    }
#pragma unroll
    for (int f = 0; f < 2; ++f) {
      int row = wc * 64 + f * 16 + lrow;
      b0[f][0] = ld_frag(Bb + row * 64 + (lk ^ swz));
      b0[f][1] = ld_frag(Bb + row * 64 + ((32 + lk) ^ swz));
    }
    if (more2) {
      gload_lds16(A + (size_t)(m0 + a_row[0]) * K + k2 + a_kc[0], An + (0 * 512 + tid) * 8);
      gload_lds16(A + (size_t)(m0 + a_row[1]) * K + k2 + a_kc[1], An + (1 * 512 + tid) * 8);
      gload_lds16(W + (size_t)(n0g + b_row[0]) * K + k2 + b_kc[0], Bn + (0 * 512 + tid) * 8);
    }
    __builtin_amdgcn_s_barrier();
    __builtin_amdgcn_s_setprio(1);
#pragma unroll
    for (int fm = 0; fm < 4; ++fm)
#pragma unroll
      for (int fn = 0; fn < 2; ++fn)
#pragma unroll
        for (int kk = 0; kk < 2; ++kk)
          acc[fm][fn] = __builtin_amdgcn_mfma_f32_16x16x32_bf16(a[fm][kk], b0[fn][kk], acc[fm][fn], 0, 0, 0);
    __builtin_amdgcn_s_setprio(0);
    __builtin_amdgcn_s_barrier();

    // ---- phase 1
#pragma unroll
    for (int f = 0; f < 2; ++f) {
      int row = wc * 64 + (2 + f) * 16 + lrow;
      b1[f][0] = ld_frag(Bb + row * 64 + (lk ^ swz));
      b1[f][1] = ld_frag(Bb + row * 64 + ((32 + lk) ^ swz));
    }
    if (more2) {
      gload_lds16(W + (size_t)(n0g + b_row[1]) * K + k2 + b_kc[1], Bn + (1 * 512 + tid) * 8);
      gload_lds16(W + (size_t)(n0g + b_row[2]) * K + k2 + b_kc[2], Bn + (2 * 512 + tid) * 8);
      gload_lds16(W + (size_t)(n0g + b_row[3]) * K + k2 + b_kc[3], Bn + (3 * 512 + tid) * 8);
    }
    __builtin_amdgcn_s_barrier();
    __builtin_amdgcn_s_setprio(1);
#pragma unroll
    for (int fm = 0; fm < 4; ++fm)
#pragma unroll
      for (int fn = 0; fn < 2; ++fn)
#pragma unroll
        for (int kk = 0; kk < 2; ++kk)
          acc[fm][2 + fn] = __builtin_amdgcn_mfma_f32_16x16x32_bf16(a[fm][kk], b1[fn][kk], acc[fm][2 + fn], 0, 0, 0);
    __builtin_amdgcn_s_setprio(0);
    if (t + 1 < NSTEP) {
      if (more2) asm volatile("s_waitcnt vmcnt(6)" ::: "memory");
      else       asm volatile("s_waitcnt vmcnt(0)" ::: "memory");
    }
    __builtin_amdgcn_s_barrier();
    cur = cur == 2 ? 0 : cur + 1;
    nx2 = nx2 == 2 ? 0 : nx2 + 1;
  }

  const int region = bx >> 2;               // 0=q, 1=k, 2=v
  const int nc0 = (bx & 3) * 256;
  const float* bias = region == 0 ? bq : region == 1 ? bk2 : bv;
  u16* dstRM = region == 0 ? qm : km;

#pragma unroll
  for (int fm = 0; fm < 4; ++fm) {
#pragma unroll
    for (int fn = 0; fn < 4; ++fn) {
      int row = m0 + wr * 64 + fm * 16 + hi * 4;
      int col = nc0 + wc * 64 + fn * 16 + lrow;
      float bv_ = bias[col];
      if (region == 2) {
        ushort4 o;
        o.x = f2bf(acc[fm][fn][0] + bv_); o.y = f2bf(acc[fm][fn][1] + bv_);
        o.z = f2bf(acc[fm][fn][2] + bv_); o.w = f2bf(acc[fm][fn][3] + bv_);
        *reinterpret_cast<ushort4*>(&vt[(size_t)col * Mm + row]) = o;
      } else {
#pragma unroll
        for (int j = 0; j < 4; ++j)
          dstRM[(size_t)(row + j) * Dd + col] = f2bf(acc[fm][fn][j] + bv_);
      }
    }
  }
}

// Out-projection GEMM: same 128x256 2-phase + triple-buffer (R15). f32 out.
__global__ __launch_bounds__(512) void gemm_out(
    const u16* __restrict__ A, const u16* __restrict__ Bt,
    const float* __restrict__ bias, float* __restrict__ C)
{
  constexpr int K = 1024, N = 1024, BK = 64, NSTEP = K / BK;
  __shared__ u16 ldsA[3][128 * 64];
  __shared__ u16 ldsB[3][256 * 64];

  const int tid = threadIdx.x;
  const int wave = tid >> 6, lane = tid & 63;
  const int wr = wave >> 2, wc = wave & 3;
  const int lrow = lane & 15, hi = lane >> 4, lk = hi * 8;
  const int swz = (lrow & 7) << 3;

  const int lin = blockIdx.y * 4 + blockIdx.x;      // 0..255
  const int nid = (lin & 7) * 32 + (lin >> 3);      // bijective (256/8=32)
  const int bx = nid % 4, by = nid / 4;
  const int m0 = by * 128;
  const int n0 = bx * 256;

  int a_row[2], a_kc[2], b_row[4], b_kc[4];
#pragma unroll
  for (int g = 0; g < 2; ++g) {
    int c = g * 512 + tid;
    a_row[g] = c >> 3;
    a_kc[g] = ((c & 7) ^ (a_row[g] & 7)) * 8;
  }
#pragma unroll
  for (int g = 0; g < 4; ++g) {
    int c = g * 512 + tid;
    b_row[g] = c >> 3;
    b_kc[g] = ((c & 7) ^ (b_row[g] & 7)) * 8;
  }

  f32x4 acc[4][4] = {};

#pragma unroll
  for (int g = 0; g < 2; ++g)
    gload_lds16(A + (size_t)(m0 + a_row[g]) * K + a_kc[g], &ldsA[0][0] + (g * 512 + tid) * 8);
#pragma unroll
  for (int g = 0; g < 4; ++g)
    gload_lds16(Bt + (size_t)(n0 + b_row[g]) * K + b_kc[g], &ldsB[0][0] + (g * 512 + tid) * 8);
#pragma unroll
  for (int g = 0; g < 2; ++g)
    gload_lds16(A + (size_t)(m0 + a_row[g]) * K + BK + a_kc[g], &ldsA[1][0] + (g * 512 + tid) * 8);
#pragma unroll
  for (int g = 0; g < 4; ++g)
    gload_lds16(Bt + (size_t)(n0 + b_row[g]) * K + BK + b_kc[g], &ldsB[1][0] + (g * 512 + tid) * 8);
  asm volatile("s_waitcnt vmcnt(6)" ::: "memory");
  __syncthreads();

  int cur = 0, nx2 = 2;
  for (int t = 0; t < NSTEP; ++t) {
    const u16* Ab = &ldsA[cur][0];
    const u16* Bb = &ldsB[cur][0];
    u16* An = &ldsA[nx2][0];
    u16* Bn = &ldsB[nx2][0];
    const int k2 = (t + 2) * BK;
    const bool more2 = (t + 2 < NSTEP);

    bf16x8 a[4][2], b0[2][2], b1[2][2];

#pragma unroll
    for (int f = 0; f < 4; ++f) {
      int row = wr * 64 + f * 16 + lrow;
      a[f][0] = ld_frag(Ab + row * 64 + (lk ^ swz));
      a[f][1] = ld_frag(Ab + row * 64 + ((32 + lk) ^ swz));
    }
#pragma unroll
    for (int f = 0; f < 2; ++f) {
      int row = wc * 64 + f * 16 + lrow;
      b0[f][0] = ld_frag(Bb + row * 64 + (lk ^ swz));
      b0[f][1] = ld_frag(Bb + row * 64 + ((32 + lk) ^ swz));
    }
    if (more2) {
      gload_lds16(A + (size_t)(m0 + a_row[0]) * K + k2 + a_kc[0], An + (0 * 512 + tid) * 8);
      gload_lds16(A + (size_t)(m0 + a_row[1]) * K + k2 + a_kc[1], An + (1 * 512 + tid) * 8);
      gload_lds16(Bt + (size_t)(n0 + b_row[0]) * K + k2 + b_kc[0], Bn + (0 * 512 + tid) * 8);
    }
    __builtin_amdgcn_s_barrier();
    __builtin_amdgcn_s_setprio(1);
#pragma unroll
    for (int fm = 0; fm < 4; ++fm)
#pragma unroll
      for (int fn = 0; fn < 2; ++fn)
#pragma unroll
        for (int kk = 0; kk < 2; ++kk)
          acc[fm][fn] = __builtin_amdgcn_mfma_f32_16x16x32_bf16(a[fm][kk], b0[fn][kk], acc[fm][fn], 0, 0, 0);
    __builtin_amdgcn_s_setprio(0);
    __builtin_amdgcn_s_barrier();

#pragma unroll
    for (int f = 0; f < 2; ++f) {
      int row = wc * 64 + (2 + f) * 16 + lrow;
      b1[f][0] = ld_frag(Bb + row * 64 + (lk ^ swz));
      b1[f][1] = ld_frag(Bb + row * 64 + ((32 + lk) ^ swz));
    }
    if (more2) {
      gload_lds16(Bt + (size_t)(n0 + b_row[1]) * K + k2 + b_kc[1], Bn + (1 * 512 + tid) * 8);
      gload_lds16(Bt + (size_t)(n0 + b_row[2]) * K + k2 + b_kc[2], Bn + (2 * 512 + tid) * 8);
      gload_lds16(Bt + (size_t)(n0 + b_row[3]) * K + k2 + b_kc[3], Bn + (3 * 512 + tid) * 8);
    }
    __builtin_amdgcn_s_barrier();
    __builtin_amdgcn_s_setprio(1);
#pragma unroll
    for (int fm = 0; fm < 4; ++fm)
#pragma unroll
      for (int fn = 0; fn < 2; ++fn)
#pragma unroll
        for (int kk = 0; kk < 2; ++kk)
          acc[fm][2 + fn] = __builtin_amdgcn_mfma_f32_16x16x32_bf16(a[fm][kk], b1[fn][kk], acc[fm][2 + fn], 0, 0, 0);
    __builtin_amdgcn_s_setprio(0);
    if (t + 1 < NSTEP) {
      if (more2) asm volatile("s_waitcnt vmcnt(6)" ::: "memory");
      else       asm volatile("s_waitcnt vmcnt(0)" ::: "memory");
    }
    __builtin_amdgcn_s_barrier();
    cur = cur == 2 ? 0 : cur + 1;
    nx2 = nx2 == 2 ? 0 : nx2 + 1;
  }

#pragma unroll
  for (int fm = 0; fm < 4; ++fm) {
#pragma unroll
    for (int fn = 0; fn < 4; ++fn) {
      int row = m0 + wr * 64 + fm * 16 + hi * 4;
      int col = n0 + wc * 64 + fn * 16 + lrow;
      float bv = bias[col];
#pragma unroll
      for (int j = 0; j < 4; ++j)
        C[(size_t)(row + j) * N + col] = acc[fm][fn][j] + bv;
    }
  }
}

// Flash attention — R15 structure reverted verbatim (best measured: 80.7us,
// 0 bank conflicts, occ 36%). R16's KVBLK=128 regressed: wrong V^T[64][128]
// swizzle (4.19M conflicts) + 64KB LDS occupancy drop. KVBLK=64, 32KB LDS,
// 2 q-blocks/wave, counted-vmcnt loop, QK back-to-back.
__global__ __launch_bounds__(512) void attn_fwd(
    const u16* __restrict__ Qm, const u16* __restrict__ Km,
    const u16* __restrict__ Vt, u16* __restrict__ Om)
{
  __shared__ u16 Ks[2][4096];
  __shared__ u16 Vs[2][4096];

  const int tid = threadIdx.x;
  const int wave = tid >> 6, lane = tid & 63;
  const int lrow = lane & 15, lk = (lane >> 4) * 8;
  const int swz = (lrow & 7) << 3;
  const int b = blockIdx.x >> 4, h = blockIdx.x & 15;
  const int rb = b * Ls;
  const int cb0 = h * DhC;
  const int q0 = blockIdx.y * 256;
  const int srow = lane >> 3;
  const int scol = ((lane & 7) ^ srow) * 8;

  const u16* kg = Km + (size_t)(rb + wave * 8 + srow) * Dd + cb0 + scol;
  const u16* vg = Vt + (size_t)(cb0 + wave * 8 + srow) * Mm + rb + scol;
  u16* ksflat = &Ks[0][0];
  u16* vsflat = &Vs[0][0];
  u16* ksl = ksflat + wave * 512;
  u16* vsl = vsflat + wave * 512;
  constexpr int LBUF = 4096;

  // prologue: Q (256x64 = 32KB) -> Ks+Vs dbuf area
#pragma unroll
  for (int g = 0; g < 4; ++g) {
    int c = wave * 4 + g;
    u16* dst = c < 16 ? ksflat + c * 512 : vsflat + (c - 16) * 512;
    gload_lds16(Qm + (size_t)(rb + q0 + c * 8 + srow) * Dd + cb0 + scol, dst);
  }
  __syncthreads();

  constexpr float SCL = 0.25f * 1.44269504088896f;
  bf16x8 aq[2][2];
#pragma unroll
  for (int t = 0; t < 2; ++t) {
    int row = wave * 32 + t * 16 + lrow;
    const u16* base = row < 128 ? ksflat + row * 64 : vsflat + (row - 128) * 64;
    aq[t][0] = ld_frag(base + (lk ^ swz));
    aq[t][1] = ld_frag(base + ((32 + lk) ^ swz));
#pragma unroll
    for (int e = 0; e < 8; e += 2) {
      unsigned d0 = cvt_pk_bf16(SCL * bf2f((u16)aq[t][0][e]), SCL * bf2f((u16)aq[t][0][e + 1]));
      unsigned d1 = cvt_pk_bf16(SCL * bf2f((u16)aq[t][1][e]), SCL * bf2f((u16)aq[t][1][e + 1]));
      aq[t][0][e] = (short)(d0 & 0xffff); aq[t][0][e + 1] = (short)(d0 >> 16);
      aq[t][1][e] = (short)(d1 & 0xffff); aq[t][1][e + 1] = (short)(d1 >> 16);
    }
  }
  __syncthreads();
  gload_lds16(kg, ksl);
  gload_lds16(vg, vsl);

  bf16x8 ones;
#pragma unroll
  for (int e = 0; e < 8; ++e) ones[e] = (short)0x3F80;

  f32x4 accO[2][4] = {};
  f32x4 acc_ps[2] = {};

#define SM_PACK(SIN, AP0, AP1)                                                 \
  {                                                                            \
    unsigned u00 = cvt_pk_bf16(__builtin_amdgcn_exp2f(SIN[0][0]), __builtin_amdgcn_exp2f(SIN[0][1])); \
    unsigned u01 = cvt_pk_bf16(__builtin_amdgcn_exp2f(SIN[0][2]), __builtin_amdgcn_exp2f(SIN[0][3])); \
    unsigned u10 = cvt_pk_bf16(__builtin_amdgcn_exp2f(SIN[1][0]), __builtin_amdgcn_exp2f(SIN[1][1])); \
    unsigned u11 = cvt_pk_bf16(__builtin_amdgcn_exp2f(SIN[1][2]), __builtin_amdgcn_exp2f(SIN[1][3])); \
    unsigned u20 = cvt_pk_bf16(__builtin_amdgcn_exp2f(SIN[2][0]), __builtin_amdgcn_exp2f(SIN[2][1])); \
    unsigned u21 = cvt_pk_bf16(__builtin_amdgcn_exp2f(SIN[2][2]), __builtin_amdgcn_exp2f(SIN[2][3])); \
    unsigned u30 = cvt_pk_bf16(__builtin_amdgcn_exp2f(SIN[3][0]), __builtin_amdgcn_exp2f(SIN[3][1])); \
    unsigned u31 = cvt_pk_bf16(__builtin_amdgcn_exp2f(SIN[3][2]), __builtin_amdgcn_exp2f(SIN[3][3])); \
    asm("v_permlane32_swap_b32 %0, %1" : "+v"(u00), "+v"(u10));                \
    asm("v_permlane16_swap_b32 %0, %1" : "+v"(u00), "+v"(u10));                \
    asm("v_permlane32_swap_b32 %0, %1" : "+v"(u01), "+v"(u11));                \
    asm("v_permlane16_swap_b32 %0, %1" : "+v"(u01), "+v"(u11));                \
    asm("v_permlane32_swap_b32 %0, %1" : "+v"(u20), "+v"(u30));                \
    asm("v_permlane16_swap_b32 %0, %1" : "+v"(u20), "+v"(u30));                \
    asm("v_permlane32_swap_b32 %0, %1" : "+v"(u21), "+v"(u31));                \
    asm("v_permlane16_swap_b32 %0, %1" : "+v"(u21), "+v"(u31));                \
    union { unsigned u[4]; bf16x8 v; } c0_, c1_;                               \
    c0_.u[0] = u00; c0_.u[1] = u01; c0_.u[2] = u10; c0_.u[3] = u11;            \
    c1_.u[0] = u20; c1_.u[1] = u21; c1_.u[2] = u30; c1_.u[3] = u31;            \
    AP0 = c0_.v; AP1 = c1_.v;                                                  \
  }

  int nb = 0;
  for (int kv0 = 0; kv0 < Ls; kv0 += 64) {
    if (kv0 + 64 < Ls) {
      int dst = (nb ^ 1) * LBUF;
      gload_lds16(kg + (size_t)(kv0 + 64) * Dd, ksl + dst);
      gload_lds16(vg + kv0 + 64, vsl + dst);
      asm volatile("s_waitcnt vmcnt(2)" ::: "memory");
    } else {
      asm volatile("s_waitcnt vmcnt(0)" ::: "memory");
    }
    __builtin_amdgcn_s_barrier();
    const u16* ks = ksflat + nb * LBUF;
    const u16* vs = vsflat + nb * LBUF;

    bf16x8 bk[4][2];
#pragma unroll
    for (int kb = 0; kb < 4; ++kb) {
      const u16* kr = ks + (kb * 16 + lrow) * 64;
      bk[kb][0] = ld_frag(kr + (lk ^ swz));
      bk[kb][1] = ld_frag(kr + ((32 + lk) ^ swz));
    }

    // QK both q-blocks back-to-back; SM below overlaps on the VALU
    f32x4 s0[4], s1[4];
    __builtin_amdgcn_s_setprio(1);
#pragma unroll
    for (int kb = 0; kb < 4; ++kb) {
      f32x4 u = {};
      u = __builtin_amdgcn_mfma_f32_16x16x32_bf16(bk[kb][0], aq[0][0], u, 0, 0, 0);
      u = __builtin_amdgcn_mfma_f32_16x16x32_bf16(bk[kb][1], aq[0][1], u, 0, 0, 0);
      s0[kb] = u;
    }
#pragma unroll
    for (int kb = 0; kb < 4; ++kb) {
      f32x4 u = {};
      u = __builtin_amdgcn_mfma_f32_16x16x32_bf16(bk[kb][0], aq[1][0], u, 0, 0, 0);
      u = __builtin_amdgcn_mfma_f32_16x16x32_bf16(bk[kb][1], aq[1][1], u, 0, 0, 0);
      s1[kb] = u;
    }
    __builtin_amdgcn_s_setprio(0);

    bf16x8 ap0[2], ap1[2];
    SM_PACK(s0, ap0[0], ap0[1]);
    SM_PACK(s1, ap1[0], ap1[1]);

#pragma unroll
    for (int kk2 = 0; kk2 < 2; ++kk2) {
      __builtin_amdgcn_s_setprio(1);
#pragma unroll
      for (int cb = 0; cb < 4; ++cb) {
        const u16* vr = vs + (cb * 16 + lrow) * 64;
        bf16x8 bv = ld_frag(vr + ((kk2 * 32 + lk) ^ swz));
        accO[0][cb] = __builtin_amdgcn_mfma_f32_16x16x32_bf16(bv, ap0[kk2], accO[0][cb], 0, 0, 0);
        accO[1][cb] = __builtin_amdgcn_mfma_f32_16x16x32_bf16(bv, ap1[kk2], accO[1][cb], 0, 0, 0);
      }
      acc_ps[0] = __builtin_amdgcn_mfma_f32_16x16x32_bf16(ones, ap0[kk2], acc_ps[0], 0, 0, 0);
      acc_ps[1] = __builtin_amdgcn_mfma_f32_16x16x32_bf16(ones, ap1[kk2], acc_ps[1], 0, 0, 0);
      __builtin_amdgcn_s_setprio(0);
    }

    if (kv0 + 64 < Ls) __builtin_amdgcn_s_barrier();
    nb ^= 1;
  }
#undef SM_PACK

#pragma unroll
  for (int t = 0; t < 2; ++t) {
    float rinv = 1.0f / acc_ps[t][0];
    const size_t orow = (size_t)(rb + q0 + wave * 32 + t * 16 + lrow) * Dd + cb0;
#pragma unroll
    for (int cb = 0; cb < 4; ++cb) {
      uint2 o;
      o.x = cvt_pk_bf16(accO[t][cb][0] * rinv, accO[t][cb][1] * rinv);
      o.y = cvt_pk_bf16(accO[t][cb][2] * rinv, accO[t][cb][3] * rinv);
      *reinterpret_cast<uint2*>(&Om[orow + cb * 16 + (lk >> 1)]) = o;
    }
  }
}

extern "C" void kernel_launch(void* const* d_in, const int* in_sizes, int n_in,
                              void* d_out, int out_size, void* d_ws, size_t ws_size,
                              hipStream_t stream) {
  (void)in_sizes; (void)n_in; (void)out_size; (void)ws_size;
  const float* x  = (const float*)d_in[0];
  const float* wq = (const float*)d_in[1];
  const float* bq = (const float*)d_in[2];
  const float* wk = (const float*)d_in[3];
  const float* bk = (const float*)d_in[4];
  const float* wv = (const float*)d_in[5];
  const float* bv = (const float*)d_in[6];
  const float* wo = (const float*)d_in[7];
  const float* bo = (const float*)d_in[8];
  float* out = (float*)d_out;

  u16* ws  = (u16*)d_ws;
  u16* xb  = ws;
  u16* wqb = xb  + (size_t)Mm * Dd;
  u16* wkb = wqb + (size_t)Dd * Dd;
  u16* wvb = wkb + (size_t)Dd * Dd;
  u16* wob = wvb + (size_t)Dd * Dd;
  u16* qm  = wob + (size_t)Dd * Dd;
  u16* km  = qm  + (size_t)Mm * Dd;
  u16* vt  = km  + (size_t)Mm * Dd;
  u16* om  = xb;

  cvt_all<<<2048, 256, 0, stream>>>(x, wq, wk, wv, wo, xb, wqb, wkb, wvb, wob);

  dim3 qkvgrid(3 * Dd / 256, Mm / 128);   // 12 x 64 = 768 blocks, zero tail
  gemm_qkv<<<qkvgrid, 512, 0, stream>>>(xb, wqb, bq, bk, bv, qm, km, vt);

  dim3 agrid(Bb * Hh, Ls / 256);          // 64 x 8 = 512 blocks, 2/CU
  attn_fwd<<<agrid, 512, 0, stream>>>(qm, km, vt, om);

  dim3 ogrid(Dd / 256, Mm / 128);         // 4 x 64 = 256 blocks, 1/CU
  gemm_out<<<ogrid, 512, 0, stream>>>(om, wob, bo, out);
}